// Round 1
// baseline (1002.723 us; speedup 1.0000x reference)
//
#include <hip/hip_runtime.h>
#include <hip/hip_fp16.h>

#define S_LEN 2048
#define DKV 64
#define NBH 32

using half8 = __attribute__((ext_vector_type(8))) _Float16;
using f32x4 = __attribute__((ext_vector_type(4))) float;

// ---------------------------------------------------------------------------
// Runtime mask-dtype detection.
// bool/int8 mask: random 0/1 bytes at every position -> nonzero at p%4==0 AND p%4!=0.
// int32 mask (0/1): only byte p%4==0 can be nonzero.
// float32 mask (0/1.0f): only bytes p%4 in {2,3} nonzero -> also "4-byte" path (!=0 works).
// flag = 1 -> treat as 4-byte elements, flag = 0 -> 1-byte elements.
// ---------------------------------------------------------------------------
__global__ void detect_mask_kernel(const unsigned char* __restrict__ mask,
                                   int* __restrict__ flag) {
  __shared__ int nz0s, nzos;
  if (threadIdx.x == 0) { nz0s = 0; nzos = 0; }
  __syncthreads();
  int nz0 = 0, nzo = 0;
  for (int i = threadIdx.x; i < 65536; i += 256) {
    unsigned char b = mask[i];
    if (b) { if ((i & 3) == 0) nz0++; else nzo++; }
  }
  atomicAdd(&nz0s, nz0);
  atomicAdd(&nzos, nzo);
  __syncthreads();
  if (threadIdx.x == 0) *flag = (nz0s > 0 && nzos > 0) ? 0 : 1;
}

// ---------------------------------------------------------------------------
// Main fused attention kernel.
// Block = 512 threads (8 waves), handles one (bh, 16-row Q tile).
// Wave w owns k-columns [w*256, w*256+256).
// ---------------------------------------------------------------------------
__global__ __launch_bounds__(512, 1)
void attn_main_kernel(const float* __restrict__ Q, const float* __restrict__ K,
                      const float* __restrict__ V, const void* __restrict__ maskv,
                      float* __restrict__ out, const int* __restrict__ flag) {
  // P tile: [16 q][2048 k] fp16, rows padded to 2056 (row stride 4112 B ->
  // 2-way (free) LDS bank pattern for both u16 writes and b128 reads).
  __shared__ __align__(16) unsigned char smem[16 * 2056 * 2];
  __shared__ float redm[8][16];
  __shared__ float reds[8][16];
  _Float16 (*P)[2056] = (_Float16 (*)[2056])smem;

  const int bh = blockIdx.y;
  const int q0 = blockIdx.x << 4;
  const int tid = threadIdx.x;
  const int w = tid >> 6;        // wave 0..7
  const int lane = tid & 63;
  const int g = lane >> 4;       // lane group 0..3
  const int c = lane & 15;       // lane-in-group 0..15
  const int k0 = w << 8;         // wave's k-column base

  const bool mask_w = (*flag) != 0;  // uniform: 4-byte mask elements?
  const unsigned char* m8 = (const unsigned char*)maskv;
  const unsigned int* m32 = (const unsigned int*)maskv;

  const float* Qb = Q + ((size_t)bh * S_LEN + q0) * DKV;
  const float* Kb = K + (size_t)bh * S_LEN * DKV;
  const float* Vb = V + (size_t)bh * S_LEN * DKV;
  const size_t mbase = ((size_t)bh * S_LEN + q0) * S_LEN;
  float* ctx_out = out + ((size_t)bh * S_LEN + q0) * DKV;
  float* attn_out = out + (size_t)NBH * S_LEN * DKV + mbase;

  // ---- Q A-fragments: lane holds Q[q0+c][t*32 + g*8 + j]
  half8 a0, a1;
  {
    const float* qr = Qb + (size_t)c * DKV + g * 8;
    f32x4 x0 = *(const f32x4*)(qr);
    f32x4 x1 = *(const f32x4*)(qr + 4);
    f32x4 y0 = *(const f32x4*)(qr + 32);
    f32x4 y1 = *(const f32x4*)(qr + 36);
#pragma unroll
    for (int j = 0; j < 4; j++) {
      a0[j] = (_Float16)x0[j]; a0[4 + j] = (_Float16)x1[j];
      a1[j] = (_Float16)y0[j]; a1[4 + j] = (_Float16)y1[j];
    }
  }

  // ---- QK^T: scores[q=g*4+e][k = k0 + n*16 + c] in acc[n][e]
  f32x4 acc[16];
#pragma unroll
  for (int n = 0; n < 16; n++) acc[n] = (f32x4)0.0f;

#pragma unroll
  for (int n = 0; n < 16; n++) {
    const float* kr = Kb + (size_t)(k0 + n * 16 + c) * DKV + g * 8;
    f32x4 x0 = *(const f32x4*)(kr);
    f32x4 x1 = *(const f32x4*)(kr + 4);
    f32x4 y0 = *(const f32x4*)(kr + 32);
    f32x4 y1 = *(const f32x4*)(kr + 36);
    half8 b0, b1;
#pragma unroll
    for (int j = 0; j < 4; j++) {
      b0[j] = (_Float16)x0[j]; b0[4 + j] = (_Float16)x1[j];
      b1[j] = (_Float16)y0[j]; b1[4 + j] = (_Float16)y1[j];
    }
    acc[n] = __builtin_amdgcn_mfma_f32_16x16x32_f16(a0, b0, acc[n], 0, 0, 0);
    acc[n] = __builtin_amdgcn_mfma_f32_16x16x32_f16(a1, b1, acc[n], 0, 0, 0);
  }

  // ---- scale + mask + per-row max
  float mx[4] = {-1e9f, -1e9f, -1e9f, -1e9f};
#pragma unroll
  for (int n = 0; n < 16; n++) {
    const int kc = k0 + n * 16 + c;
#pragma unroll
    for (int e = 0; e < 4; e++) {
      const size_t mi = mbase + (size_t)(g * 4 + e) * S_LEN + kc;
      bool masked;
      if (mask_w) masked = (__builtin_nontemporal_load(&m32[mi]) != 0u);
      else        masked = (__builtin_nontemporal_load(&m8[mi]) != 0);
      float s = masked ? -1e9f : acc[n][e] * 0.125f;
      acc[n][e] = s;
      mx[e] = fmaxf(mx[e], s);
    }
  }
  // reduce across the 16 lanes that share a row (xor bits 0..3 stay in group)
#pragma unroll
  for (int off = 1; off < 16; off <<= 1) {
#pragma unroll
    for (int e = 0; e < 4; e++)
      mx[e] = fmaxf(mx[e], __shfl_xor(mx[e], off, 64));
  }
  if (c == 0) {
#pragma unroll
    for (int e = 0; e < 4; e++) redm[w][g * 4 + e] = mx[e];
  }
  __syncthreads();
  float m[4], sm[4];
#pragma unroll
  for (int e = 0; e < 4; e++) {
    float v = redm[0][g * 4 + e];
#pragma unroll
    for (int ww = 1; ww < 8; ww++) v = fmaxf(v, redm[ww][g * 4 + e]);
    m[e] = v;
    sm[e] = 0.0f;
  }

  // ---- exp + row sum
#pragma unroll
  for (int n = 0; n < 16; n++) {
#pragma unroll
    for (int e = 0; e < 4; e++) {
      float p = __expf(acc[n][e] - m[e]);
      acc[n][e] = p;
      sm[e] += p;
    }
  }
#pragma unroll
  for (int off = 1; off < 16; off <<= 1) {
#pragma unroll
    for (int e = 0; e < 4; e++) sm[e] += __shfl_xor(sm[e], off, 64);
  }
  if (c == 0) {
#pragma unroll
    for (int e = 0; e < 4; e++) reds[w][g * 4 + e] = sm[e];
  }
  __syncthreads();
  float inv[4];
#pragma unroll
  for (int e = 0; e < 4; e++) {
    float z = 0.0f;
#pragma unroll
    for (int ww = 0; ww < 8; ww++) z += reds[ww][g * 4 + e];
    inv[e] = 1.0f / z;
  }

  // ---- write attn (nontemporal fp32) + stash normalized P (fp16) in LDS
#pragma unroll
  for (int n = 0; n < 16; n++) {
    const int kc = k0 + n * 16 + c;
#pragma unroll
    for (int e = 0; e < 4; e++) {
      float v = acc[n][e] * inv[e];
      __builtin_nontemporal_store(v, &attn_out[(size_t)(g * 4 + e) * S_LEN + kc]);
      P[g * 4 + e][kc] = (_Float16)v;
    }
  }
  __syncthreads();

  // ---- PV: context partial [16 q][64 d] per wave over its k range
  f32x4 ctx[4];
#pragma unroll
  for (int n = 0; n < 4; n++) ctx[n] = (f32x4)0.0f;

  for (int ks = 0; ks < 8; ks++) {
    const int kb = k0 + ks * 32;
    half8 pa = *(const half8*)&P[c][kb + g * 8];  // A-frag: P[q=c][kb+g*8+j]
#pragma unroll
    for (int n = 0; n < 4; n++) {
      const float* vp = Vb + (size_t)(kb + g * 8) * DKV + n * 16 + c;
      half8 vb;
#pragma unroll
      for (int j = 0; j < 8; j++) vb[j] = (_Float16)vp[(size_t)j * DKV];
      ctx[n] = __builtin_amdgcn_mfma_f32_16x16x32_f16(pa, vb, ctx[n], 0, 0, 0);
    }
  }
  __syncthreads();  // all P reads done; reuse smem for reduction

  float* red2 = (float*)smem;  // [8 waves][16 q][64 d]
#pragma unroll
  for (int n = 0; n < 4; n++) {
#pragma unroll
    for (int e = 0; e < 4; e++)
      red2[((w * 16) + g * 4 + e) * 64 + n * 16 + c] = ctx[n][e];
  }
  __syncthreads();
  for (int i = tid; i < 16 * 64; i += 512) {
    int q = i >> 6, d = i & 63;
    float ssum = 0.0f;
#pragma unroll
    for (int ww = 0; ww < 8; ww++) ssum += red2[((ww * 16) + q) * 64 + d];
    ctx_out[(size_t)q * DKV + d] = ssum;
  }
}

extern "C" void kernel_launch(void* const* d_in, const int* in_sizes, int n_in,
                              void* d_out, int out_size, void* d_ws, size_t ws_size,
                              hipStream_t stream) {
  (void)in_sizes; (void)n_in; (void)out_size; (void)ws_size;
  const float* Q = (const float*)d_in[0];
  const float* K = (const float*)d_in[1];
  const float* V = (const float*)d_in[2];
  const void* mask = d_in[3];
  int* flag = (int*)d_ws;

  hipLaunchKernelGGL(detect_mask_kernel, dim3(1), dim3(256), 0, stream,
                     (const unsigned char*)mask, flag);
  hipLaunchKernelGGL(attn_main_kernel, dim3(128, 32), dim3(512), 0, stream,
                     Q, K, V, mask, (float*)d_out, flag);
}

// Round 2
// 758.076 us; speedup vs baseline: 1.3227x; 1.3227x over previous
//
#include <hip/hip_runtime.h>
#include <hip/hip_fp16.h>

#define S_LEN 2048
#define DKV 64
#define NBH 32

using half8 = __attribute__((ext_vector_type(8))) _Float16;
using half4 = __attribute__((ext_vector_type(4))) _Float16;
using f32x4 = __attribute__((ext_vector_type(4))) float;

// ---------------------------------------------------------------------------
// Runtime mask-dtype detection (1-byte bool vs 4-byte int/float 0/1).
// ---------------------------------------------------------------------------
__global__ void detect_mask_kernel(const unsigned char* __restrict__ mask,
                                   int* __restrict__ flag) {
  __shared__ int nz0s, nzos;
  if (threadIdx.x == 0) { nz0s = 0; nzos = 0; }
  __syncthreads();
  int nz0 = 0, nzo = 0;
  for (int i = threadIdx.x; i < 65536; i += 256) {
    unsigned char b = mask[i];
    if (b) { if ((i & 3) == 0) nz0++; else nzo++; }
  }
  atomicAdd(&nz0s, nz0);
  atomicAdd(&nzos, nzo);
  __syncthreads();
  if (threadIdx.x == 0) *flag = (nz0s > 0 && nzos > 0) ? 0 : 1;
}

// ---------------------------------------------------------------------------
// fp32 -> fp16 elementwise (Q, K). One thread per float4.
// ---------------------------------------------------------------------------
__global__ void convert_f32_f16_kernel(const float* __restrict__ src,
                                       _Float16* __restrict__ dst) {
  size_t i = (size_t)blockIdx.x * blockDim.x + threadIdx.x;
  f32x4 v = *(const f32x4*)(src + i * 4);
  half4 h;
#pragma unroll
  for (int j = 0; j < 4; j++) h[j] = (_Float16)v[j];
  *(half4*)(dst + i * 4) = h;
}

// ---------------------------------------------------------------------------
// V [bh][k][d] fp32  ->  VT [bh][d][k] fp16.  Block: 64k x 64d tile.
// ---------------------------------------------------------------------------
__global__ void transpose_v_kernel(const float* __restrict__ V,
                                   _Float16* __restrict__ VT) {
  __shared__ _Float16 t[64][68];
  const int bh = blockIdx.y;
  const int k0 = blockIdx.x * 64;
  const float* Vb = V + ((size_t)bh * S_LEN + k0) * DKV;
#pragma unroll
  for (int it = 0; it < 4; it++) {
    int idx = threadIdx.x + it * 256;
    int kl = idx >> 4;
    int dq = (idx & 15) * 4;
    f32x4 v = *(const f32x4*)(Vb + (size_t)kl * DKV + dq);
#pragma unroll
    for (int j = 0; j < 4; j++) t[kl][dq + j] = (_Float16)v[j];
  }
  __syncthreads();
  _Float16* VTb = VT + (size_t)bh * DKV * S_LEN;
#pragma unroll
  for (int it = 0; it < 4; it++) {
    int idx = threadIdx.x + it * 256;
    int d = idx >> 4;
    int kq = (idx & 15) * 4;
    half4 h;
#pragma unroll
    for (int j = 0; j < 4; j++) h[j] = t[kq + j][d];
    *(half4*)(VTb + (size_t)d * S_LEN + k0 + kq) = h;
  }
}

// ---------------------------------------------------------------------------
// Fast fused attention. Block = 512 thr (8 waves) = one (bh, 16-row Q tile);
// wave w owns k-columns [w*256, (w+1)*256). P transposed through a per-wave
// 16x40 fp16 LDS chunk (wave-synchronous, no barrier) per 32-k slice.
// ---------------------------------------------------------------------------
__global__ __launch_bounds__(512, 4)
void attn_fast_kernel(const _Float16* __restrict__ QH, const _Float16* __restrict__ KH,
                      const _Float16* __restrict__ VT, const void* __restrict__ maskv,
                      float* __restrict__ out, const int* __restrict__ flag) {
  __shared__ __align__(16) unsigned char smem[32768];     // red2 [8][16][64] f32
  __shared__ __align__(16) _Float16 pbuf[8][16][40];      // per-wave P chunk
  __shared__ float redm[8][16];
  __shared__ float reds[8][16];

  const int bh = blockIdx.y;
  const int q0 = blockIdx.x << 4;
  const int tid = threadIdx.x;
  const int w = tid >> 6;
  const int lane = tid & 63;
  const int g = lane >> 4;
  const int c = lane & 15;
  const int k0 = w << 8;

  const bool mask_w = (*flag) != 0;
  const unsigned char* m8 = (const unsigned char*)maskv;
  const unsigned int* m32 = (const unsigned int*)maskv;

  const size_t mbase = ((size_t)bh * S_LEN + q0) * S_LEN;
  float* ctx_out = out + ((size_t)bh * S_LEN + q0) * DKV;
  float* attn_out = out + (size_t)NBH * S_LEN * DKV + mbase;

  // ---- Q A-fragments
  const _Float16* qr = QH + ((size_t)bh * S_LEN + q0 + c) * DKV + g * 8;
  half8 a0 = *(const half8*)qr;
  half8 a1 = *(const half8*)(qr + 32);

  // ---- QK^T: scores[q=g*4+e][k=k0+n*16+c] in acc[n][e]
  f32x4 acc[16];
#pragma unroll
  for (int n = 0; n < 16; n++) acc[n] = (f32x4)0.0f;
#pragma unroll
  for (int n = 0; n < 16; n++) {
    const _Float16* kr = KH + ((size_t)bh * S_LEN + k0 + n * 16 + c) * DKV + g * 8;
    half8 b0 = *(const half8*)kr;
    half8 b1 = *(const half8*)(kr + 32);
    acc[n] = __builtin_amdgcn_mfma_f32_16x16x32_f16(a0, b0, acc[n], 0, 0, 0);
    acc[n] = __builtin_amdgcn_mfma_f32_16x16x32_f16(a1, b1, acc[n], 0, 0, 0);
  }

  // ---- scale + mask + per-row max
  float mx[4] = {-1e9f, -1e9f, -1e9f, -1e9f};
#pragma unroll
  for (int n = 0; n < 16; n++) {
    const int kc = k0 + n * 16 + c;
#pragma unroll
    for (int e = 0; e < 4; e++) {
      const size_t mi = mbase + (size_t)(g * 4 + e) * S_LEN + kc;
      bool masked;
      if (mask_w) masked = (__builtin_nontemporal_load(&m32[mi]) != 0u);
      else        masked = (__builtin_nontemporal_load(&m8[mi]) != 0);
      float s = masked ? -1e9f : acc[n][e] * 0.125f;
      acc[n][e] = s;
      mx[e] = fmaxf(mx[e], s);
    }
  }
#pragma unroll
  for (int off = 1; off < 16; off <<= 1) {
#pragma unroll
    for (int e = 0; e < 4; e++)
      mx[e] = fmaxf(mx[e], __shfl_xor(mx[e], off, 64));
  }
  if (c == 0) {
#pragma unroll
    for (int e = 0; e < 4; e++) redm[w][g * 4 + e] = mx[e];
  }
  __syncthreads();
  float m[4], sm[4];
#pragma unroll
  for (int e = 0; e < 4; e++) {
    float v = redm[0][g * 4 + e];
#pragma unroll
    for (int ww = 1; ww < 8; ww++) v = fmaxf(v, redm[ww][g * 4 + e]);
    m[e] = v;
    sm[e] = 0.0f;
  }

  // ---- exp + row sum
#pragma unroll
  for (int n = 0; n < 16; n++) {
#pragma unroll
    for (int e = 0; e < 4; e++) {
      float p = __expf(acc[n][e] - m[e]);
      acc[n][e] = p;
      sm[e] += p;
    }
  }
#pragma unroll
  for (int off = 1; off < 16; off <<= 1) {
#pragma unroll
    for (int e = 0; e < 4; e++) sm[e] += __shfl_xor(sm[e], off, 64);
  }
  if (c == 0) {
#pragma unroll
    for (int e = 0; e < 4; e++) reds[w][g * 4 + e] = sm[e];
  }
  __syncthreads();
  float inv[4];
#pragma unroll
  for (int e = 0; e < 4; e++) {
    float z = 0.0f;
#pragma unroll
    for (int ww = 0; ww < 8; ww++) z += reds[ww][g * 4 + e];
    inv[e] = 1.0f / z;
  }

  // ---- PV loop: per 32-k slice, transpose P via per-wave LDS chunk,
  //      write attn (fp32, from fp16 P), MFMA with coalesced VT loads.
  f32x4 ctx[4];
#pragma unroll
  for (int n = 0; n < 4; n++) ctx[n] = (f32x4)0.0f;

  const _Float16* VTb = VT + (size_t)bh * DKV * S_LEN;
#pragma unroll
  for (int ks = 0; ks < 8; ks++) {
#pragma unroll
    for (int mhalf = 0; mhalf < 2; mhalf++) {
      const int n = ks * 2 + mhalf;
#pragma unroll
      for (int e = 0; e < 4; e++)
        pbuf[w][g * 4 + e][mhalf * 16 + c] = (_Float16)(acc[n][e] * inv[e]);
    }
    // wave-synchronous: same wave wrote, same wave reads (compiler orders)
    half8 pa = *(const half8*)&pbuf[w][c][g * 8];

    // attn output: row c, 8 consecutive k -> two float4 nontemporal stores
    f32x4 lo, hi;
#pragma unroll
    for (int j = 0; j < 4; j++) { lo[j] = (float)pa[j]; hi[j] = (float)pa[4 + j]; }
    float* ao = attn_out + (size_t)c * S_LEN + k0 + ks * 32 + g * 8;
    __builtin_nontemporal_store(lo, (f32x4*)ao);
    __builtin_nontemporal_store(hi, (f32x4*)(ao + 4));

#pragma unroll
    for (int n = 0; n < 4; n++) {
      const _Float16* vp = VTb + (size_t)(n * 16 + c) * S_LEN + k0 + ks * 32 + g * 8;
      half8 vb = *(const half8*)vp;
      ctx[n] = __builtin_amdgcn_mfma_f32_16x16x32_f16(pa, vb, ctx[n], 0, 0, 0);
    }
  }
  __syncthreads();  // PV done; reuse smem for ctx reduction

  float* red2 = (float*)smem;  // [8 waves][16 q][64 d]
#pragma unroll
  for (int n = 0; n < 4; n++) {
#pragma unroll
    for (int e = 0; e < 4; e++)
      red2[((w * 16) + g * 4 + e) * 64 + n * 16 + c] = ctx[n][e];
  }
  __syncthreads();
  for (int i = tid; i < 16 * 64; i += 512) {
    int q = i >> 6, d = i & 63;
    float ssum = 0.0f;
#pragma unroll
    for (int ww = 0; ww < 8; ww++) ssum += red2[((ww * 16) + q) * 64 + d];
    ctx_out[(size_t)q * DKV + d] = ssum;
  }
}

// ---------------------------------------------------------------------------
// Fallback (previous working kernel) if ws is too small for staging buffers.
// ---------------------------------------------------------------------------
__global__ __launch_bounds__(512, 1)
void attn_slow_kernel(const float* __restrict__ Q, const float* __restrict__ K,
                      const float* __restrict__ V, const void* __restrict__ maskv,
                      float* __restrict__ out, const int* __restrict__ flag) {
  __shared__ __align__(16) unsigned char smem[16 * 2056 * 2];
  __shared__ float redm[8][16];
  __shared__ float reds[8][16];
  _Float16 (*P)[2056] = (_Float16 (*)[2056])smem;

  const int bh = blockIdx.y;
  const int q0 = blockIdx.x << 4;
  const int tid = threadIdx.x;
  const int w = tid >> 6;
  const int lane = tid & 63;
  const int g = lane >> 4;
  const int c = lane & 15;
  const int k0 = w << 8;

  const bool mask_w = (*flag) != 0;
  const unsigned char* m8 = (const unsigned char*)maskv;
  const unsigned int* m32 = (const unsigned int*)maskv;

  const float* Qb = Q + ((size_t)bh * S_LEN + q0) * DKV;
  const float* Kb = K + (size_t)bh * S_LEN * DKV;
  const float* Vb = V + (size_t)bh * S_LEN * DKV;
  const size_t mbase = ((size_t)bh * S_LEN + q0) * S_LEN;
  float* ctx_out = out + ((size_t)bh * S_LEN + q0) * DKV;
  float* attn_out = out + (size_t)NBH * S_LEN * DKV + mbase;

  half8 a0, a1;
  {
    const float* qrow = Qb + (size_t)c * DKV + g * 8;
    f32x4 x0 = *(const f32x4*)(qrow);
    f32x4 x1 = *(const f32x4*)(qrow + 4);
    f32x4 y0 = *(const f32x4*)(qrow + 32);
    f32x4 y1 = *(const f32x4*)(qrow + 36);
#pragma unroll
    for (int j = 0; j < 4; j++) {
      a0[j] = (_Float16)x0[j]; a0[4 + j] = (_Float16)x1[j];
      a1[j] = (_Float16)y0[j]; a1[4 + j] = (_Float16)y1[j];
    }
  }

  f32x4 acc[16];
#pragma unroll
  for (int n = 0; n < 16; n++) acc[n] = (f32x4)0.0f;
#pragma unroll
  for (int n = 0; n < 16; n++) {
    const float* kr = Kb + (size_t)(k0 + n * 16 + c) * DKV + g * 8;
    f32x4 x0 = *(const f32x4*)(kr);
    f32x4 x1 = *(const f32x4*)(kr + 4);
    f32x4 y0 = *(const f32x4*)(kr + 32);
    f32x4 y1 = *(const f32x4*)(kr + 36);
    half8 b0, b1;
#pragma unroll
    for (int j = 0; j < 4; j++) {
      b0[j] = (_Float16)x0[j]; b0[4 + j] = (_Float16)x1[j];
      b1[j] = (_Float16)y0[j]; b1[4 + j] = (_Float16)y1[j];
    }
    acc[n] = __builtin_amdgcn_mfma_f32_16x16x32_f16(a0, b0, acc[n], 0, 0, 0);
    acc[n] = __builtin_amdgcn_mfma_f32_16x16x32_f16(a1, b1, acc[n], 0, 0, 0);
  }

  float mx[4] = {-1e9f, -1e9f, -1e9f, -1e9f};
#pragma unroll
  for (int n = 0; n < 16; n++) {
    const int kc = k0 + n * 16 + c;
#pragma unroll
    for (int e = 0; e < 4; e++) {
      const size_t mi = mbase + (size_t)(g * 4 + e) * S_LEN + kc;
      bool masked;
      if (mask_w) masked = (__builtin_nontemporal_load(&m32[mi]) != 0u);
      else        masked = (__builtin_nontemporal_load(&m8[mi]) != 0);
      float s = masked ? -1e9f : acc[n][e] * 0.125f;
      acc[n][e] = s;
      mx[e] = fmaxf(mx[e], s);
    }
  }
#pragma unroll
  for (int off = 1; off < 16; off <<= 1) {
#pragma unroll
    for (int e = 0; e < 4; e++)
      mx[e] = fmaxf(mx[e], __shfl_xor(mx[e], off, 64));
  }
  if (c == 0) {
#pragma unroll
    for (int e = 0; e < 4; e++) redm[w][g * 4 + e] = mx[e];
  }
  __syncthreads();
  float m[4], sm[4];
#pragma unroll
  for (int e = 0; e < 4; e++) {
    float v = redm[0][g * 4 + e];
#pragma unroll
    for (int ww = 1; ww < 8; ww++) v = fmaxf(v, redm[ww][g * 4 + e]);
    m[e] = v;
    sm[e] = 0.0f;
  }
#pragma unroll
  for (int n = 0; n < 16; n++) {
#pragma unroll
    for (int e = 0; e < 4; e++) {
      float p = __expf(acc[n][e] - m[e]);
      acc[n][e] = p;
      sm[e] += p;
    }
  }
#pragma unroll
  for (int off = 1; off < 16; off <<= 1) {
#pragma unroll
    for (int e = 0; e < 4; e++) sm[e] += __shfl_xor(sm[e], off, 64);
  }
  if (c == 0) {
#pragma unroll
    for (int e = 0; e < 4; e++) reds[w][g * 4 + e] = sm[e];
  }
  __syncthreads();
  float inv[4];
#pragma unroll
  for (int e = 0; e < 4; e++) {
    float z = 0.0f;
#pragma unroll
    for (int ww = 0; ww < 8; ww++) z += reds[ww][g * 4 + e];
    inv[e] = 1.0f / z;
  }
#pragma unroll
  for (int n = 0; n < 16; n++) {
    const int kc = k0 + n * 16 + c;
#pragma unroll
    for (int e = 0; e < 4; e++) {
      float v = acc[n][e] * inv[e];
      __builtin_nontemporal_store(v, &attn_out[(size_t)(g * 4 + e) * S_LEN + kc]);
      P[g * 4 + e][kc] = (_Float16)v;
    }
  }
  __syncthreads();

  f32x4 ctx[4];
#pragma unroll
  for (int n = 0; n < 4; n++) ctx[n] = (f32x4)0.0f;
  for (int ks = 0; ks < 8; ks++) {
    const int kb = k0 + ks * 32;
    half8 pa = *(const half8*)&P[c][kb + g * 8];
#pragma unroll
    for (int n = 0; n < 4; n++) {
      const float* vp = Vb + (size_t)(kb + g * 8) * DKV + n * 16 + c;
      half8 vb;
#pragma unroll
      for (int j = 0; j < 8; j++) vb[j] = (_Float16)vp[(size_t)j * DKV];
      ctx[n] = __builtin_amdgcn_mfma_f32_16x16x32_f16(pa, vb, ctx[n], 0, 0, 0);
    }
  }
  __syncthreads();

  float* red2 = (float*)smem;
#pragma unroll
  for (int n = 0; n < 4; n++) {
#pragma unroll
    for (int e = 0; e < 4; e++)
      red2[((w * 16) + g * 4 + e) * 64 + n * 16 + c] = ctx[n][e];
  }
  __syncthreads();
  for (int i = tid; i < 16 * 64; i += 512) {
    int q = i >> 6, d = i & 63;
    float ssum = 0.0f;
#pragma unroll
    for (int ww = 0; ww < 8; ww++) ssum += red2[((ww * 16) + q) * 64 + d];
    ctx_out[(size_t)q * DKV + d] = ssum;
  }
}

extern "C" void kernel_launch(void* const* d_in, const int* in_sizes, int n_in,
                              void* d_out, int out_size, void* d_ws, size_t ws_size,
                              hipStream_t stream) {
  (void)in_sizes; (void)n_in; (void)out_size;
  const float* Q = (const float*)d_in[0];
  const float* K = (const float*)d_in[1];
  const float* V = (const float*)d_in[2];
  const void* mask = d_in[3];

  const size_t HBYTES = (size_t)NBH * S_LEN * DKV * sizeof(_Float16);  // 8 MB
  const size_t NEED = 256 + 3 * HBYTES;

  int* flag = (int*)d_ws;
  hipLaunchKernelGGL(detect_mask_kernel, dim3(1), dim3(256), 0, stream,
                     (const unsigned char*)mask, flag);

  if (ws_size >= NEED) {
    _Float16* QH = (_Float16*)((char*)d_ws + 256);
    _Float16* KH = (_Float16*)((char*)d_ws + 256 + HBYTES);
    _Float16* VT = (_Float16*)((char*)d_ws + 256 + 2 * HBYTES);
    const int n4 = NBH * S_LEN * DKV / 4;  // float4s per tensor
    hipLaunchKernelGGL(convert_f32_f16_kernel, dim3(n4 / 256), dim3(256), 0, stream, Q, QH);
    hipLaunchKernelGGL(convert_f32_f16_kernel, dim3(n4 / 256), dim3(256), 0, stream, K, KH);
    hipLaunchKernelGGL(transpose_v_kernel, dim3(S_LEN / 64, NBH), dim3(256), 0, stream, V, VT);
    hipLaunchKernelGGL(attn_fast_kernel, dim3(128, 32), dim3(512), 0, stream,
                       QH, KH, VT, mask, (float*)d_out, flag);
  } else {
    hipLaunchKernelGGL(attn_slow_kernel, dim3(128, 32), dim3(512), 0, stream,
                       Q, K, V, mask, (float*)d_out, flag);
  }
}

// Round 4
// 530.343 us; speedup vs baseline: 1.8907x; 1.4294x over previous
//
#include <hip/hip_runtime.h>
#include <hip/hip_fp16.h>

#define S_LEN 2048
#define DKV 64
#define NBH 32
#define CTX_ELEMS ((size_t)NBH * S_LEN * DKV)

using half8 = __attribute__((ext_vector_type(8))) _Float16;
using half4 = __attribute__((ext_vector_type(4))) _Float16;
using f32x4 = __attribute__((ext_vector_type(4))) float;
using u32x4 = __attribute__((ext_vector_type(4))) unsigned int;

#define MFMA16(a, b, c) __builtin_amdgcn_mfma_f32_16x16x32_f16((a), (b), (c), 0, 0, 0)

// ---------------------------------------------------------------------------
// Runtime mask-dtype detection (1-byte bool vs 4-byte int/float 0/1).
// ---------------------------------------------------------------------------
__global__ void detect_mask_kernel(const unsigned char* __restrict__ mask,
                                   int* __restrict__ flag) {
  __shared__ int nz0s, nzos;
  if (threadIdx.x == 0) { nz0s = 0; nzos = 0; }
  __syncthreads();
  int nz0 = 0, nzo = 0;
  for (int i = threadIdx.x; i < 65536; i += 256) {
    unsigned char b = mask[i];
    if (b) { if ((i & 3) == 0) nz0++; else nzo++; }
  }
  atomicAdd(&nz0s, nz0);
  atomicAdd(&nzos, nzo);
  __syncthreads();
  if (threadIdx.x == 0) *flag = (nz0s > 0 && nzos > 0) ? 0 : 1;
}

// ---------------------------------------------------------------------------
// Pack mask -> 1 bit per element. Bit f of dword bits[f>>5] = (mask[f] != 0).
// Grid 2048 x 256 threads, 64 iters, fully coalesced 16 B/lane reads.
// ---------------------------------------------------------------------------
__global__ void pack_mask_kernel(const void* __restrict__ maskv,
                                 const int* __restrict__ flag,
                                 unsigned int* __restrict__ bits) {
  __shared__ unsigned char nib[256];
  const bool w4 = (*flag) != 0;
  const unsigned int* m32 = (const unsigned int*)maskv;
  const int tid = threadIdx.x;
  for (int it = 0; it < 64; ++it) {
    const size_t e0 = ((size_t)blockIdx.x * 64 + it) * 1024;  // element base
    const size_t ei = e0 + (size_t)tid * 4;
    unsigned int nv;
    if (w4) {
      u32x4 v = __builtin_nontemporal_load((const u32x4*)(m32 + ei));
      nv = (v[0] ? 1u : 0u) | (v[1] ? 2u : 0u) | (v[2] ? 4u : 0u) | (v[3] ? 8u : 0u);
    } else {
      unsigned int b = __builtin_nontemporal_load(m32 + (ei >> 2));
      nv = ((b & 0xffu) ? 1u : 0u) | ((b & 0xff00u) ? 2u : 0u) |
           ((b & 0xff0000u) ? 4u : 0u) | ((b & 0xff000000u) ? 8u : 0u);
    }
    __syncthreads();              // previous iter's readers done
    nib[tid] = (unsigned char)nv;
    __syncthreads();
    if (tid < 32) {
      unsigned int dw = 0;
#pragma unroll
      for (int t = 0; t < 8; ++t)
        dw |= ((unsigned int)nib[tid * 8 + t]) << (t * 4);
      bits[(e0 >> 5) + tid] = dw;
    }
  }
}

// ---------------------------------------------------------------------------
// fp32 -> fp16 elementwise (Q, K).
// ---------------------------------------------------------------------------
__global__ void convert_f32_f16_kernel(const float* __restrict__ src,
                                       _Float16* __restrict__ dst) {
  size_t i = (size_t)blockIdx.x * blockDim.x + threadIdx.x;
  f32x4 v = *(const f32x4*)(src + i * 4);
  half4 h;
#pragma unroll
  for (int j = 0; j < 4; j++) h[j] = (_Float16)v[j];
  *(half4*)(dst + i * 4) = h;
}

// ---------------------------------------------------------------------------
// V [bh][k][d] fp32 -> VT [bh][d][k] fp16.
// ---------------------------------------------------------------------------
__global__ void transpose_v_kernel(const float* __restrict__ V,
                                   _Float16* __restrict__ VT) {
  __shared__ _Float16 t[64][68];
  const int bh = blockIdx.y;
  const int k0 = blockIdx.x * 64;
  const float* Vb = V + ((size_t)bh * S_LEN + k0) * DKV;
#pragma unroll
  for (int it = 0; it < 4; it++) {
    int idx = threadIdx.x + it * 256;
    int kl = idx >> 4;
    int dq = (idx & 15) * 4;
    f32x4 v = *(const f32x4*)(Vb + (size_t)kl * DKV + dq);
#pragma unroll
    for (int j = 0; j < 4; j++) t[kl][dq + j] = (_Float16)v[j];
  }
  __syncthreads();
  _Float16* VTb = VT + (size_t)bh * DKV * S_LEN;
#pragma unroll
  for (int it = 0; it < 4; it++) {
    int idx = threadIdx.x + it * 256;
    int d = idx >> 4;
    int kq = (idx & 15) * 4;
    half4 h;
#pragma unroll
    for (int j = 0; j < 4; j++) h[j] = t[kq + j][d];
    *(half4*)(VTb + (size_t)d * S_LEN + k0 + kq) = h;
  }
}

// ---------------------------------------------------------------------------
// Main attention, v3: 256 thr (4 waves), each wave owns one 16-row q-tile,
// sweeps all 2048 k. Two-pass wave-local softmax, zero barriers.
// ---------------------------------------------------------------------------
__global__ __launch_bounds__(256, 4)
void attn_v3_kernel(const _Float16* __restrict__ QH, const _Float16* __restrict__ KH,
                    const _Float16* __restrict__ VT, const unsigned int* __restrict__ bits,
                    float* __restrict__ out) {
  __shared__ __align__(16) _Float16 pbuf[4][16][40];  // per-wave P slice [16 q][32 k]

  const int tid = threadIdx.x;
  const int w = tid >> 6;
  const int lane = tid & 63;
  const int g = lane >> 4;
  const int c = lane & 15;

  // XCD-chunked swizzle (1024 % 8 == 0 -> bijective): each XCD gets 4 bh.
  const int phys = blockIdx.x;
  const int orig = (phys & 7) * 128 + (phys >> 3);
  const int tile = orig * 4 + w;          // 0..4095
  const int bh = tile >> 7;
  const int q0 = (tile & 127) << 4;

  const _Float16* qp = QH + ((size_t)(bh * S_LEN + q0 + c)) * DKV + g * 8;
  const half8 a0 = *(const half8*)qp;
  const half8 a1 = *(const half8*)(qp + 32);

  const _Float16* Kb = KH + (size_t)bh * S_LEN * DKV;
  const unsigned int* bq = bits + ((size_t)(bh * S_LEN + q0)) * (S_LEN / 32);

  float m[4], Z[4];
#pragma unroll
  for (int e = 0; e < 4; e++) { m[e] = -3e38f; Z[e] = 0.0f; }

  // ---------------- pass 1: row max + denominator (online, per-lane) --------
  for (int kt4 = 0; kt4 < 16; ++kt4) {
    u32x4 mb[4];
#pragma unroll
    for (int e = 0; e < 4; e++)
      mb[e] = *(const u32x4*)(bq + (size_t)(g * 4 + e) * (S_LEN / 32) + kt4 * 4);
#pragma unroll
    for (int sub = 0; sub < 4; ++sub) {
      const int kt = kt4 * 4 + sub;
      const _Float16* kp = Kb + ((size_t)(kt * 32 + c)) * DKV + g * 8;
      half8 k00 = *(const half8*)kp;
      half8 k01 = *(const half8*)(kp + 32);
      half8 k10 = *(const half8*)(kp + 16 * DKV);
      half8 k11 = *(const half8*)(kp + 16 * DKV + 32);
      f32x4 acc0 = (f32x4)0.0f, acc1 = (f32x4)0.0f;
      acc0 = MFMA16(a0, k00, acc0);
      acc0 = MFMA16(a1, k01, acc0);
      acc1 = MFMA16(a0, k10, acc1);
      acc1 = MFMA16(a1, k11, acc1);
#pragma unroll
      for (int e = 0; e < 4; e++) {
        const unsigned int bw = mb[e][sub];
        float s0 = ((bw >> c) & 1u) ? -1e9f : acc0[e] * 0.125f;
        float s1 = ((bw >> (16 + c)) & 1u) ? -1e9f : acc1[e] * 0.125f;
        float pm = fmaxf(s0, s1);
        float nm = fmaxf(m[e], pm);
        Z[e] = Z[e] * __expf(m[e] - nm) + __expf(s0 - nm) + __expf(s1 - nm);
        m[e] = nm;
      }
    }
  }
  // merge the 16 c-lanes sharing each row
#pragma unroll
  for (int off = 1; off < 16; off <<= 1) {
#pragma unroll
    for (int e = 0; e < 4; e++) {
      float om = __shfl_xor(m[e], off, 64);
      float oz = __shfl_xor(Z[e], off, 64);
      float nm = fmaxf(m[e], om);
      Z[e] = Z[e] * __expf(m[e] - nm) + oz * __expf(om - nm);
      m[e] = nm;
    }
  }
  float invZ[4];
#pragma unroll
  for (int e = 0; e < 4; e++) invZ[e] = 1.0f / Z[e];

  // ---------------- pass 2: recompute scores, write attn, PV ---------------
  f32x4 ctx[4];
#pragma unroll
  for (int nn = 0; nn < 4; nn++) ctx[nn] = (f32x4)0.0f;

  const _Float16* Vb = VT + (size_t)bh * DKV * S_LEN;
  float* attn_base = out + CTX_ELEMS + ((size_t)(bh * S_LEN + q0)) * S_LEN;

  for (int kt4 = 0; kt4 < 16; ++kt4) {
    u32x4 mb[4];
#pragma unroll
    for (int e = 0; e < 4; e++)
      mb[e] = *(const u32x4*)(bq + (size_t)(g * 4 + e) * (S_LEN / 32) + kt4 * 4);
#pragma unroll
    for (int sub = 0; sub < 4; ++sub) {
      const int kt = kt4 * 4 + sub;
      const _Float16* kp = Kb + ((size_t)(kt * 32 + c)) * DKV + g * 8;
      half8 k00 = *(const half8*)kp;
      half8 k01 = *(const half8*)(kp + 32);
      half8 k10 = *(const half8*)(kp + 16 * DKV);
      half8 k11 = *(const half8*)(kp + 16 * DKV + 32);
      f32x4 acc0 = (f32x4)0.0f, acc1 = (f32x4)0.0f;
      acc0 = MFMA16(a0, k00, acc0);
      acc0 = MFMA16(a1, k01, acc0);
      acc1 = MFMA16(a0, k10, acc1);
      acc1 = MFMA16(a1, k11, acc1);
#pragma unroll
      for (int e = 0; e < 4; e++) {
        const unsigned int bw = mb[e][sub];
        float s0 = ((bw >> c) & 1u) ? -1e9f : acc0[e] * 0.125f;
        float s1 = ((bw >> (16 + c)) & 1u) ? -1e9f : acc1[e] * 0.125f;
        float p0 = __expf(s0 - m[e]) * invZ[e];
        float p1 = __expf(s1 - m[e]) * invZ[e];
        pbuf[w][g * 4 + e][c] = (_Float16)p0;        // col k = c
        pbuf[w][g * 4 + e][16 + c] = (_Float16)p1;   // col k = 16 + c
      }
      // wave-synchronous LDS (same wave wrote, same wave reads)
      half8 pa = *(const half8*)&pbuf[w][c][g * 8];

      // attn stores: 2 instructions x 1 KB fully contiguous (8 rows x 128 B)
#pragma unroll
      for (int s = 0; s < 2; s++) {
        const int r = (lane >> 3) + s * 8;
        const int c4 = (lane & 7) * 4;
        half4 h = *(const half4*)&pbuf[w][r][c4];
        f32x4 o;
#pragma unroll
        for (int j = 0; j < 4; j++) o[j] = (float)h[j];
        __builtin_nontemporal_store(o,
            (f32x4*)(attn_base + (size_t)r * S_LEN + kt * 32 + c4));
      }
      // PV
#pragma unroll
      for (int nn = 0; nn < 4; nn++) {
        const _Float16* vp = Vb + (size_t)(nn * 16 + c) * S_LEN + kt * 32 + g * 8;
        half8 vb = *(const half8*)vp;
        ctx[nn] = MFMA16(pa, vb, ctx[nn]);
      }
    }
  }

  // ---------------- context store (full 64 B sectors) ----------------------
  float* cb = out + ((size_t)(bh * S_LEN + q0)) * DKV;
#pragma unroll
  for (int nn = 0; nn < 4; nn++) {
#pragma unroll
    for (int e = 0; e < 4; e++) {
      __builtin_nontemporal_store(ctx[nn][e],
          cb + (size_t)(g * 4 + e) * DKV + nn * 16 + c);
    }
  }
}

// ---------------------------------------------------------------------------
// Fallback (R1 kernel, no workspace needed beyond flag) if ws is too small.
// ---------------------------------------------------------------------------
__global__ __launch_bounds__(512, 1)
void attn_slow_kernel(const float* __restrict__ Q, const float* __restrict__ K,
                      const float* __restrict__ V, const void* __restrict__ maskv,
                      float* __restrict__ out, const int* __restrict__ flag) {
  __shared__ __align__(16) unsigned char smem[16 * 2056 * 2];
  __shared__ float redm[8][16];
  __shared__ float reds[8][16];
  _Float16 (*P)[2056] = (_Float16 (*)[2056])smem;

  const int bh = blockIdx.y;
  const int q0 = blockIdx.x << 4;
  const int tid = threadIdx.x;
  const int w = tid >> 6;
  const int lane = tid & 63;
  const int g = lane >> 4;
  const int c = lane & 15;
  const int k0 = w << 8;

  const bool mask_w = (*flag) != 0;
  const unsigned char* m8 = (const unsigned char*)maskv;
  const unsigned int* m32 = (const unsigned int*)maskv;

  const float* Qb = Q + ((size_t)bh * S_LEN + q0) * DKV;
  const float* Kb = K + (size_t)bh * S_LEN * DKV;
  const float* Vb = V + (size_t)bh * S_LEN * DKV;
  const size_t mbase = ((size_t)bh * S_LEN + q0) * S_LEN;
  float* ctx_out = out + ((size_t)bh * S_LEN + q0) * DKV;
  float* attn_out = out + CTX_ELEMS + mbase;

  half8 a0, a1;
  {
    const float* qrow = Qb + (size_t)c * DKV + g * 8;
    f32x4 x0 = *(const f32x4*)(qrow);
    f32x4 x1 = *(const f32x4*)(qrow + 4);
    f32x4 y0 = *(const f32x4*)(qrow + 32);
    f32x4 y1 = *(const f32x4*)(qrow + 36);
#pragma unroll
    for (int j = 0; j < 4; j++) {
      a0[j] = (_Float16)x0[j]; a0[4 + j] = (_Float16)x1[j];
      a1[j] = (_Float16)y0[j]; a1[4 + j] = (_Float16)y1[j];
    }
  }

  f32x4 acc[16];
#pragma unroll
  for (int n = 0; n < 16; n++) acc[n] = (f32x4)0.0f;
#pragma unroll
  for (int n = 0; n < 16; n++) {
    const float* kr = Kb + (size_t)(k0 + n * 16 + c) * DKV + g * 8;
    f32x4 x0 = *(const f32x4*)(kr);
    f32x4 x1 = *(const f32x4*)(kr + 4);
    f32x4 y0 = *(const f32x4*)(kr + 32);
    f32x4 y1 = *(const f32x4*)(kr + 36);
    half8 b0, b1;
#pragma unroll
    for (int j = 0; j < 4; j++) {
      b0[j] = (_Float16)x0[j]; b0[4 + j] = (_Float16)x1[j];
      b1[j] = (_Float16)y0[j]; b1[4 + j] = (_Float16)y1[j];
    }
    acc[n] = MFMA16(a0, b0, acc[n]);
    acc[n] = MFMA16(a1, b1, acc[n]);
  }

  float mx[4] = {-1e9f, -1e9f, -1e9f, -1e9f};
#pragma unroll
  for (int n = 0; n < 16; n++) {
    const int kc = k0 + n * 16 + c;
#pragma unroll
    for (int e = 0; e < 4; e++) {
      const size_t mi = mbase + (size_t)(g * 4 + e) * S_LEN + kc;
      bool masked;
      if (mask_w) masked = (__builtin_nontemporal_load(&m32[mi]) != 0u);
      else        masked = (__builtin_nontemporal_load(&m8[mi]) != 0);
      float s = masked ? -1e9f : acc[n][e] * 0.125f;
      acc[n][e] = s;
      mx[e] = fmaxf(mx[e], s);
    }
  }
#pragma unroll
  for (int off = 1; off < 16; off <<= 1) {
#pragma unroll
    for (int e = 0; e < 4; e++)
      mx[e] = fmaxf(mx[e], __shfl_xor(mx[e], off, 64));
  }
  if (c == 0) {
#pragma unroll
    for (int e = 0; e < 4; e++) redm[w][g * 4 + e] = mx[e];
  }
  __syncthreads();
  float m[4], sm[4];
#pragma unroll
  for (int e = 0; e < 4; e++) {
    float v = redm[0][g * 4 + e];
#pragma unroll
    for (int ww = 1; ww < 8; ww++) v = fmaxf(v, redm[ww][g * 4 + e]);
    m[e] = v;
    sm[e] = 0.0f;
  }
#pragma unroll
  for (int n = 0; n < 16; n++) {
#pragma unroll
    for (int e = 0; e < 4; e++) {
      float p = __expf(acc[n][e] - m[e]);
      acc[n][e] = p;
      sm[e] += p;
    }
  }
#pragma unroll
  for (int off = 1; off < 16; off <<= 1) {
#pragma unroll
    for (int e = 0; e < 4; e++) sm[e] += __shfl_xor(sm[e], off, 64);
  }
  if (c == 0) {
#pragma unroll
    for (int e = 0; e < 4; e++) reds[w][g * 4 + e] = sm[e];
  }
  __syncthreads();
  float inv[4];
#pragma unroll
  for (int e = 0; e < 4; e++) {
    float z = 0.0f;
#pragma unroll
    for (int ww = 0; ww < 8; ww++) z += reds[ww][g * 4 + e];
    inv[e] = 1.0f / z;
  }
#pragma unroll
  for (int n = 0; n < 16; n++) {
    const int kc = k0 + n * 16 + c;
#pragma unroll
    for (int e = 0; e < 4; e++) {
      float v = acc[n][e] * inv[e];
      __builtin_nontemporal_store(v, &attn_out[(size_t)(g * 4 + e) * S_LEN + kc]);
      P[g * 4 + e][kc] = (_Float16)v;
    }
  }
  __syncthreads();

  f32x4 ctx[4];
#pragma unroll
  for (int n = 0; n < 4; n++) ctx[n] = (f32x4)0.0f;
  for (int ks = 0; ks < 8; ks++) {
    const int kb = k0 + ks * 32;
    half8 pa = *(const half8*)&P[c][kb + g * 8];
#pragma unroll
    for (int n = 0; n < 4; n++) {
      const float* vp = Vb + (size_t)(kb + g * 8) * DKV + n * 16 + c;
      half8 vb;
#pragma unroll
      for (int j = 0; j < 8; j++) vb[j] = (_Float16)vp[(size_t)j * DKV];
      ctx[n] = MFMA16(pa, vb, ctx[n]);
    }
  }
  __syncthreads();

  float* red2 = (float*)smem;
#pragma unroll
  for (int n = 0; n < 4; n++) {
#pragma unroll
    for (int e = 0; e < 4; e++)
      red2[((w * 16) + g * 4 + e) * 64 + n * 16 + c] = ctx[n][e];
  }
  __syncthreads();
  for (int i = tid; i < 16 * 64; i += 512) {
    int q = i >> 6, d = i & 63;
    float ssum = 0.0f;
#pragma unroll
    for (int ww = 0; ww < 8; ww++) ssum += red2[((ww * 16) + q) * 64 + d];
    ctx_out[(size_t)q * DKV + d] = ssum;
  }
}

extern "C" void kernel_launch(void* const* d_in, const int* in_sizes, int n_in,
                              void* d_out, int out_size, void* d_ws, size_t ws_size,
                              hipStream_t stream) {
  (void)in_sizes; (void)n_in; (void)out_size;
  const float* Q = (const float*)d_in[0];
  const float* K = (const float*)d_in[1];
  const float* V = (const float*)d_in[2];
  const void* mask = d_in[3];

  const size_t HBYTES = (size_t)NBH * S_LEN * DKV * sizeof(_Float16);       // 8 MB
  const size_t BITBYTES = (size_t)NBH * S_LEN * (S_LEN / 32) * 4;           // 16 MB
  const size_t NEED = 256 + 3 * HBYTES + BITBYTES;

  int* flag = (int*)d_ws;
  hipLaunchKernelGGL(detect_mask_kernel, dim3(1), dim3(256), 0, stream,
                     (const unsigned char*)mask, flag);

  if (ws_size >= NEED) {
    _Float16* QH = (_Float16*)((char*)d_ws + 256);
    _Float16* KH = (_Float16*)((char*)d_ws + 256 + HBYTES);
    _Float16* VT = (_Float16*)((char*)d_ws + 256 + 2 * HBYTES);
    unsigned int* bits = (unsigned int*)((char*)d_ws + 256 + 3 * HBYTES);
    const int n4 = NBH * S_LEN * DKV / 4;
    hipLaunchKernelGGL(pack_mask_kernel, dim3(2048), dim3(256), 0, stream,
                       mask, flag, bits);
    hipLaunchKernelGGL(convert_f32_f16_kernel, dim3(n4 / 256), dim3(256), 0, stream, Q, QH);
    hipLaunchKernelGGL(convert_f32_f16_kernel, dim3(n4 / 256), dim3(256), 0, stream, K, KH);
    hipLaunchKernelGGL(transpose_v_kernel, dim3(S_LEN / 64, NBH), dim3(256), 0, stream, V, VT);
    hipLaunchKernelGGL(attn_v3_kernel, dim3(1024), dim3(256), 0, stream,
                       QH, KH, VT, bits, (float*)d_out);
  } else {
    hipLaunchKernelGGL(attn_slow_kernel, dim3(128, 32), dim3(512), 0, stream,
                       Q, K, V, mask, (float*)d_out, flag);
  }
}